// Round 3
// baseline (252.542 us; speedup 1.0000x reference)
//
#include <hip/hip_runtime.h>
#include <math.h>

#define T_ 32
#define B_ 16
#define V_ 30000
#define D_ 300
#define DQKV_ 150
#define K_ 10
#define G_ 32
#define N_ 320      // K*G
#define S_ 25000
#define SLICES 10
#define V4_PER_SLICE 750          // (V/4)/SLICES
#define F4_FILL_PER_SLICE 625     // (S/4)/SLICES
#define CANDS 100                 // SLICES * K
#define NTA 256
#define NTB 256

__device__ __forceinline__ bool better(float av, int ai, float bv, int bi) {
    // ranks (av,ai) strictly before (bv,bi): higher value, ties -> lower index
    return (av > bv) || (av == bv && ai < bi);
}

// ---------------- Kernel A: row-slice fill + partial top-10 ----------------
__global__ __launch_bounds__(NTA) void topk_slice_kernel(
    const float* __restrict__ pred,   // [T*B, V]
    float* __restrict__ out,          // [T*B, S]
    float* __restrict__ wsv,          // [T*B*SLICES*K]
    int*   __restrict__ wsi)
{
    const int row   = blockIdx.x / SLICES;
    const int slice = blockIdx.x % SLICES;
    const int tid   = threadIdx.x;
    const int lane  = tid & 63;
    const int wave  = tid >> 6;

    __shared__ float wredv[4];
    __shared__ int   wredi[4];
    __shared__ int   sbi;

    // fill this slice of the output row with log(1e-8)
    const float FILL = -18.420680743952367f;
    {
        float4 f4 = make_float4(FILL, FILL, FILL, FILL);
        float4* orow4 = (float4*)(out + (size_t)row * S_) + slice * F4_FILL_PER_SLICE;
        for (int i = tid; i < F4_FILL_PER_SLICE; i += NTA) orow4[i] = f4;
    }

    // batched loads (explicit MLP=3) of this slice's 750 float4
    const float4* p4 = (const float4*)(pred + (size_t)row * V_) + slice * V4_PER_SLICE;
    const float4 NEG = make_float4(-INFINITY, -INFINITY, -INFINITY, -INFINITY);
    int i0 = tid, i1 = tid + NTA, i2 = tid + 2 * NTA;
    float4 v0 = (i0 < V4_PER_SLICE) ? p4[i0] : NEG;
    float4 v1 = (i1 < V4_PER_SLICE) ? p4[i1] : NEG;
    float4 v2 = (i2 < V4_PER_SLICE) ? p4[i2] : NEG;

    float tv[K_];
    int   ti[K_];
    #pragma unroll
    for (int s = 0; s < K_; ++s) { tv[s] = -INFINITY; ti[s] = 0x7fffffff; }

    const int gbase = slice * (V4_PER_SLICE * 4);
    float4 vv[3] = {v0, v1, v2};
    int    ib[3] = {i0, i1, i2};
    #pragma unroll
    for (int u = 0; u < 3; ++u) {
        float vals[4] = {vv[u].x, vv[u].y, vv[u].z, vv[u].w};
        #pragma unroll
        for (int c = 0; c < 4; ++c) {
            float val = vals[c];
            int   idx = (ib[u] < V4_PER_SLICE) ? gbase + ib[u] * 4 + c : 0x7fffffff;
            if (better(val, idx, tv[K_-1], ti[K_-1])) {
                tv[K_-1] = val; ti[K_-1] = idx;
                #pragma unroll
                for (int s = K_-1; s > 0; --s) {
                    if (better(tv[s], ti[s], tv[s-1], ti[s-1])) {
                        float a = tv[s]; tv[s] = tv[s-1]; tv[s-1] = a;
                        int   b = ti[s]; ti[s] = ti[s-1]; ti[s-1] = b;
                    }
                }
            }
        }
    }

    // block top-10 via 10 register-argmax passes
    for (int p = 0; p < K_; ++p) {
        float bv = tv[0]; int bi = ti[0];
        #pragma unroll
        for (int s = 1; s < K_; ++s)
            if (better(tv[s], ti[s], bv, bi)) { bv = tv[s]; bi = ti[s]; }
        #pragma unroll
        for (int off = 32; off > 0; off >>= 1) {
            float ov = __shfl_xor(bv, off, 64);
            int   oi = __shfl_xor(bi, off, 64);
            if (better(ov, oi, bv, bi)) { bv = ov; bi = oi; }
        }
        if (lane == 0) { wredv[wave] = bv; wredi[wave] = bi; }
        __syncthreads();
        if (tid == 0) {
            float xv = wredv[0]; int xi = wredi[0];
            #pragma unroll
            for (int w = 1; w < 4; ++w)
                if (better(wredv[w], wredi[w], xv, xi)) { xv = wredv[w]; xi = wredi[w]; }
            sbi = xi;
            wsv[blockIdx.x * K_ + p] = xv;
            wsi[blockIdx.x * K_ + p] = xi;
        }
        __syncthreads();
        int win = sbi;
        #pragma unroll
        for (int s = 0; s < K_; ++s)
            if (ti[s] == win) tv[s] = -INFINITY;
    }
}

// ------------- Kernel B: combine + attention + softmax + scatter -----------
__global__ __launch_bounds__(NTB) void attn_row_kernel(
    const float* __restrict__ lc,     // [T*B, D]
    const float* __restrict__ SC,     // [S, D]
    const float* __restrict__ Wq,     // [D, DQKV]
    const float* __restrict__ Wk,     // [D, DQKV]
    const int*   __restrict__ nbt,    // [V, G] int32
    const float* __restrict__ wsv,
    const int*   __restrict__ wsi,
    float* __restrict__ out)          // [T*B, S]
{
    const int row  = blockIdx.x;
    const int tid  = threadIdx.x;
    const int lane = tid & 63;
    const int wave = tid >> 6;

    __shared__ float wredv[4];
    __shared__ int   wredi[4];
    __shared__ int   sbi;
    __shared__ int   topg[K_];
    __shared__ float lcs[D_];
    __shared__ float qs[DQKV_];
    __shared__ __align__(16) float qks[D_];
    __shared__ int   nidx[N_];
    __shared__ float lg[N_];
    __shared__ float smax, slogsum;

    float* outrow = out + (size_t)row * S_;

    // ---- combine 100 slice candidates -> global top-10 ----
    float cv = -INFINITY; int ci = 0x7fffffff;
    if (tid < CANDS) { cv = wsv[row * CANDS + tid]; ci = wsi[row * CANDS + tid]; }
    for (int p = 0; p < K_; ++p) {
        float bv = cv; int bi = ci;
        #pragma unroll
        for (int off = 32; off > 0; off >>= 1) {
            float ov = __shfl_xor(bv, off, 64);
            int   oi = __shfl_xor(bi, off, 64);
            if (better(ov, oi, bv, bi)) { bv = ov; bi = oi; }
        }
        if (lane == 0) { wredv[wave] = bv; wredi[wave] = bi; }
        __syncthreads();
        if (tid == 0) {
            float xv = wredv[0]; int xi = wredi[0];
            #pragma unroll
            for (int w = 1; w < 4; ++w)
                if (better(wredv[w], wredi[w], xv, xi)) { xv = wredv[w]; xi = wredi[w]; }
            sbi = xi;
            topg[p] = xi;
        }
        __syncthreads();
        if (ci == sbi) cv = -INFINITY;
        __syncthreads();
    }

    // ---- neighbours + location context ----
    for (int n = tid; n < N_; n += NTB) {
        int g = topg[n >> 5];
        nidx[n] = nbt[g * G_ + (n & 31)];
    }
    for (int d = tid; d < D_; d += NTB) lcs[d] = lc[(size_t)row * D_ + d];
    __syncthreads();

    // ---- q = lcs @ Wq  [150], 2 threads per output ----
    for (int t = tid; t < 2 * DQKV_; t += NTB) {
        int j = t >> 1, h = t & 1;
        float acc = 0.f;
        int d0 = h * 150;
        for (int d = d0; d < d0 + 150; ++d) acc += lcs[d] * Wq[d * DQKV_ + j];
        acc += __shfl_xor(acc, 1, 64);
        if (h == 0) qs[j] = acc;
    }
    __syncthreads();

    // ---- qk[d] = Wk[d,:] . q  [300], 2 threads per output ----
    for (int t = tid; t < 2 * D_; t += NTB) {
        int d = t >> 1, h = t & 1;
        const float* wrow = Wk + d * DQKV_;
        float acc = 0.f;
        int j0 = h * 75;
        for (int j = j0; j < j0 + 75; ++j) acc += wrow[j] * qs[j];
        acc += __shfl_xor(acc, 1, 64);
        if (h == 0) qks[d] = acc;
    }
    __syncthreads();

    // ---- logits[n] = (qk . SC[nidx[n]]) / sqrt(150): 4 lanes per dot ----
    const float ISC = 0.08164965809277260327f;   // 1/sqrt(150)
    {
        const int hs[5] = {0, 19, 38, 57, 75};
        for (int t = tid; t < 4 * N_; t += NTB) {   // 1280 lanes, 5 full iters
            int n = t >> 2, h = t & 3;
            const float4* sc4 = (const float4*)(SC + (size_t)nidx[n] * D_);
            const float4* q4  = (const float4*)qks;
            float acc = 0.f;
            for (int d = hs[h]; d < hs[h + 1]; ++d) {
                float4 a = sc4[d], b = q4[d];
                acc += a.x * b.x + a.y * b.y + a.z * b.z + a.w * b.w;
            }
            acc += __shfl_xor(acc, 1, 64);
            acc += __shfl_xor(acc, 2, 64);
            if (h == 0) lg[n] = acc * ISC;
        }
    }
    __syncthreads();

    // ---- softmax stats over 320 logits ----
    float m = -INFINITY;
    for (int n = tid; n < N_; n += NTB) m = fmaxf(m, lg[n]);
    #pragma unroll
    for (int off = 32; off > 0; off >>= 1) m = fmaxf(m, __shfl_xor(m, off, 64));
    if (lane == 0) wredv[wave] = m;
    __syncthreads();
    if (tid == 0) smax = fmaxf(fmaxf(wredv[0], wredv[1]), fmaxf(wredv[2], wredv[3]));
    __syncthreads();
    m = smax;

    float ssum = 0.f;
    for (int n = tid; n < N_; n += NTB) ssum += expf(lg[n] - m);
    #pragma unroll
    for (int off = 32; off > 0; off >>= 1) ssum += __shfl_xor(ssum, off, 64);
    if (lane == 0) wredv[wave] = ssum;
    __syncthreads();
    if (tid == 0) slogsum = logf(wredv[0] + wredv[1] + wredv[2] + wredv[3]);
    __syncthreads();
    const float lsum = slogsum;

    // ---- scatter log-probs, numpy last-write-wins on duplicates ----
    for (int n = tid; n < N_; n += NTB) {
        int sidx = nidx[n];
        bool last = true;
        for (int n2 = n + 1; n2 < N_; ++n2)
            if (nidx[n2] == sidx) { last = false; break; }
        if (last) outrow[sidx] = (lg[n] - m) - lsum;
    }
}

extern "C" void kernel_launch(void* const* d_in, const int* in_sizes, int n_in,
                              void* d_out, int out_size, void* d_ws, size_t ws_size,
                              hipStream_t stream) {
    const float* pred = (const float*)d_in[0];
    const float* lc   = (const float*)d_in[1];
    const float* SC   = (const float*)d_in[2];
    const float* Wq   = (const float*)d_in[3];
    const float* Wk   = (const float*)d_in[4];
    const int*   nbt  = (const int*)d_in[5];
    float* out = (float*)d_out;

    const int nrows   = T_ * B_;
    const int nblocksA = nrows * SLICES;
    float* wsv = (float*)d_ws;
    int*   wsi = (int*)(wsv + (size_t)nblocksA * K_);

    topk_slice_kernel<<<dim3(nblocksA), dim3(NTA), 0, stream>>>(pred, out, wsv, wsi);
    attn_row_kernel<<<dim3(nrows), dim3(NTB), 0, stream>>>(
        lc, SC, Wq, Wk, nbt, wsv, wsi, out);
}